// Round 1
// baseline (252.547 us; speedup 1.0000x reference)
//
#include <hip/hip_runtime.h>
#include <math.h>

#define EPS 1e-6f
#define BIGF 1e30f
#define DMAX 8

__device__ __forceinline__ float waveSumF(float v) {
    #pragma unroll
    for (int m = 1; m < 64; m <<= 1) v += __shfl_xor(v, m, 64);
    return v;
}
__device__ __forceinline__ int waveSumI(int v) {
    #pragma unroll
    for (int m = 1; m < 64; m <<= 1) v += __shfl_xor(v, m, 64);
    return v;
}

// accF/accI share one 16-word buffer:
// F[0]=cal_sum F[1]=bf_sum F[2]=cx_sum F[3]=pcp_sum
// I[4]=cal_cnt I[5]=trip_cnt I[6]=ncalls I[7]=nputs

__global__ void k_scalars(const float* __restrict__ geom, const float* __restrict__ liq,
                          const float* __restrict__ iv,
                          float* lwA, float* tvA, float* lmA, float* tenA, int* cpA,
                          int* accI, int N) {
    int i = blockIdx.x * blockDim.x + threadIdx.x;
    int ic = 0, ip = 0;
    if (i < N) {
        float lm = geom[3*i], ten = geom[3*i+1], cp = geom[3*i+2];
        lmA[i] = lm; tenA[i] = ten;
        ic = (cp > 0.5f) ? 1 : 0;
        ip = (cp < 0.5f) ? 1 : 0;
        cpA[i] = ic;
        lwA[i] = 1.0f / (1.0f + expf(-liq[4*i+3]));
        float v = iv[i];
        tvA[i] = v * v * fmaxf(ten, EPS);
    }
    int sc = waveSumI(ic), sp = waveSumI(ip);
    if ((threadIdx.x & 63) == 0) {
        if (sc) atomicAdd(&accI[6], sc);
        if (sp) atomicAdd(&accI[7], sp);
    }
}

// one wave per node: L2 norm of 256-float embedding row
__global__ void k_norms(const float* __restrict__ emb, float* enA, int N, int ED) {
    int wave = (blockIdx.x * blockDim.x + threadIdx.x) >> 6;
    int lane = threadIdx.x & 63;
    if (wave >= N) return;
    const float* row = emb + (size_t)wave * ED;
    float s = 0.f;
    for (int t = lane; t < ED; t += 64) { float v = row[t]; s += v * v; }
    s = waveSumF(s);
    if (lane == 0) enA[wave] = sqrtf(s);
}

__global__ void k_calendar(const int* __restrict__ em, const float* __restrict__ tenA,
                           const float* __restrict__ lwA, const float* __restrict__ tvA,
                           float* accF, int* accI, int Em) {
    int e = blockIdx.x * blockDim.x + threadIdx.x;
    float c = 0.f; int n = 0;
    if (e < Em) {
        int s = em[e], d = em[Em + e];
        if (tenA[s] < tenA[d] - EPS) {
            n = 1;
            c = fminf(lwA[s], lwA[d]) * fmaxf(tvA[s] - tvA[d], 0.0f);
        }
    }
    c = waveSumF(c); n = waveSumI(n);
    if ((threadIdx.x & 63) == 0) {
        if (c != 0.f) atomicAdd(&accF[0], c);
        if (n) atomicAdd(&accI[4], n);
    }
}

__global__ void k_adj(const int* __restrict__ es, int* cnt, int* nbr, int Es) {
    int e = blockIdx.x * blockDim.x + threadIdx.x;
    if (e >= Es) return;
    int s = es[e], d = es[Es + e];
    int p = atomicAdd(&cnt[s], 1); if (p < DMAX) nbr[s * DMAX + p] = d;
    p = atomicAdd(&cnt[d], 1);     if (p < DMAX) nbr[d * DMAX + p] = s;
}

__global__ void k_btf(const int* __restrict__ cnt, const int* __restrict__ nbr,
                      const int* __restrict__ cpA, const float* __restrict__ lmA,
                      const float* __restrict__ lwA, const float* __restrict__ tvA,
                      const float* __restrict__ enA,
                      float* accF, int* accI, int N) {
    int i = blockIdx.x * blockDim.x + threadIdx.x;
    float bf = 0.f, cx = 0.f; int tc = 0;
    if (i < N) {
        int m = cnt[i]; if (m > DMAX) m = DMAX;
        int ids[DMAX]; float key[DMAX]; int mv = 0;
        for (int t = 0; t < m; t++) {
            int nb = nbr[i * DMAX + t];
            if (cpA[nb]) {
                float k = lmA[nb];
                int p = mv++;
                while (p > 0 && key[p-1] > k) { key[p] = key[p-1]; ids[p] = ids[p-1]; p--; }
                key[p] = k; ids[p] = nb;
            }
        }
        if (cpA[i] && mv >= 3) {
            float lwi = lwA[i];
            for (int j = 0; j + 2 < mv; j++) {
                int n1 = ids[j], n2 = ids[j+1], n3 = ids[j+2];
                float lm1 = key[j], lm2 = key[j+1], lm3 = key[j+2];
                float denom = lm3 - lm1 + EPS;
                float alpha = (lm3 - lm2) / denom;
                float beta  = (lm2 - lm1) / denom;
                float bviol = fmaxf(alpha * tvA[n1] + beta * tvA[n3] - tvA[n2], 0.f);
                float xviol = fmaxf(enA[n2] - (alpha * enA[n1] + (1.0f - alpha) * enA[n3]), 0.f);
                float w = lwi * lwA[n2];
                bf += w * bviol; cx += w * xviol; tc++;
            }
        }
    }
    bf = waveSumF(bf); cx = waveSumF(cx); tc = waveSumI(tc);
    if ((threadIdx.x & 63) == 0) {
        if (bf != 0.f) atomicAdd(&accF[1], bf);
        if (cx != 0.f) atomicAdd(&accF[2], cx);
        if (tc) atomicAdd(&accI[5], tc);
    }
}

// argmin over puts of (lm_i-lm_j)^2 + (ten_i-ten_j)^2; first-index tiebreak
// key = (float_bits(dist) << 32) | j  → atomicMin reproduces np.argmin semantics
__global__ void k_argmin(const float* __restrict__ lmA, const float* __restrict__ tenA,
                         const int* __restrict__ cpA,
                         unsigned long long* bestkey, int N, int chunk) {
    __shared__ float slm[256], sten[256];
    __shared__ int sput[256];
    int i = blockIdx.x * blockDim.x + threadIdx.x;
    float lmi = (i < N) ? lmA[i] : 0.f;
    float teni = (i < N) ? tenA[i] : 0.f;
    int j0 = blockIdx.y * chunk;
    int j1 = min(j0 + chunk, N);
    float mind = INFINITY; int minj = 0;
    for (int t0 = j0; t0 < j1; t0 += 256) {
        __syncthreads();
        int jj = t0 + threadIdx.x;
        if (jj < N) {
            slm[threadIdx.x] = lmA[jj];
            sten[threadIdx.x] = tenA[jj];
            sput[threadIdx.x] = cpA[jj] ? 0 : 1;
        }
        __syncthreads();
        int tend = min(256, j1 - t0);
        for (int t = 0; t < tend; t++) {
            float dl = lmi - slm[t];
            float dt = teni - sten[t];
            float d = sput[t] ? (dl * dl + dt * dt) : BIGF;
            if (d < mind) { mind = d; minj = t0 + t; }  // strict < keeps lowest j
        }
    }
    if (i < N) {
        unsigned long long key =
            ((unsigned long long)__float_as_uint(mind) << 32) | (unsigned int)minj;
        atomicMin(&bestkey[i], key);
    }
}

// one wave per call node: ||emb_i - emb_best||^2, weighted into pcp_sum
__global__ void k_pcp(const float* __restrict__ emb,
                      const unsigned long long* __restrict__ bestkey,
                      const int* __restrict__ cpA, const float* __restrict__ lwA,
                      float* accF, int N, int ED) {
    int wave = (blockIdx.x * blockDim.x + threadIdx.x) >> 6;
    int lane = threadIdx.x & 63;
    if (wave >= N) return;
    if (!cpA[wave]) return;                 // wave-uniform branch
    int b = (int)(bestkey[wave] & 0xffffffffULL);
    if (b < 0 || b >= N) return;
    const float* ri = emb + (size_t)wave * ED;
    const float* rb = emb + (size_t)b * ED;
    float s = 0.f;
    for (int t = lane; t < ED; t += 64) { float dd = ri[t] - rb[t]; s += dd * dd; }
    s = waveSumF(s);
    if (lane == 0) atomicAdd(&accF[3], lwA[wave] * lwA[b] * s);
}

__global__ void k_fin(const float* __restrict__ accF, const int* __restrict__ accI,
                      float* out) {
    float cal = (accI[4] > 0) ? accF[0] / (float)max(accI[4], 1) : 0.f;
    int tcount = accI[5];
    float bf = (tcount > 0) ? accF[1] / (float)tcount : 0.f;
    float cx = (tcount > 0) ? accF[2] / (float)tcount : 0.f;
    float pcp = (accI[6] > 0 && accI[7] > 0) ? accF[3] / (float)max(accI[6], 1) : 0.f;
    out[0] = cal;
    out[1] = bf;
    out[2] = pcp;
    out[3] = cx;
    out[4] = cal + bf + 0.5f * pcp + 0.5f * cx;
}

extern "C" void kernel_launch(void* const* d_in, const int* in_sizes, int n_in,
                              void* d_out, int out_size, void* d_ws, size_t ws_size,
                              hipStream_t stream) {
    const float* emb  = (const float*)d_in[0];   // (N,256)
    const float* iv   = (const float*)d_in[1];   // (N,1)
    const float* geom = (const float*)d_in[2];   // (N,3)
    const float* liq  = (const float*)d_in[3];   // (N,4)
    const int*   es   = (const int*)d_in[4];     // (2,Es)
    const int*   em   = (const int*)d_in[5];     // (2,Em)

    const int N  = in_sizes[1];
    const int ED = in_sizes[0] / N;
    const int Es = in_sizes[4] / 2;
    const int Em = in_sizes[5] / 2;

    // workspace layout (bytes from d_ws):
    float* lwA  = (float*)d_ws;          // N
    float* tvA  = lwA + N;               // N
    float* enA  = tvA + N;               // N
    float* lmA  = enA + N;               // N
    float* tenA = lmA + N;               // N
    int*   cpA  = (int*)(tenA + N);      // N
    int*   cnt  = cpA + N;               // N
    int*   nbr  = cnt + N;               // 8N
    unsigned long long* bestkey = (unsigned long long*)(nbr + DMAX * N); // N (8B-aligned: 60N bytes off)
    float* accF = (float*)(bestkey + N); // 16 words
    int*   accI = (int*)accF;

    size_t used = (size_t)(15 * N) * 4 + (size_t)N * 8 + 64;
    hipMemsetAsync(d_ws, 0, used, stream);
    hipMemsetAsync((void*)bestkey, 0xFF, (size_t)N * 8, stream);

    const int B = 256;
    k_scalars<<<(N + B - 1) / B, B, 0, stream>>>(geom, liq, iv, lwA, tvA, lmA, tenA, cpA, accI, N);
    k_norms<<<(N * 64 + B - 1) / B, B, 0, stream>>>(emb, enA, N, ED);
    k_calendar<<<(Em + B - 1) / B, B, 0, stream>>>(em, tenA, lwA, tvA, accF, accI, Em);
    k_adj<<<(Es + B - 1) / B, B, 0, stream>>>(es, cnt, nbr, Es);
    k_btf<<<(N + B - 1) / B, B, 0, stream>>>(cnt, nbr, cpA, lmA, lwA, tvA, enA, accF, accI, N);

    int splitY = 8;
    int chunk = (N + splitY - 1) / splitY;
    chunk = ((chunk + 255) / 256) * 256;
    dim3 ag((N + B - 1) / B, splitY);
    k_argmin<<<ag, B, 0, stream>>>(lmA, tenA, cpA, bestkey, N, chunk);

    k_pcp<<<(N * 64 + B - 1) / B, B, 0, stream>>>(emb, bestkey, cpA, lwA, accF, N, ED);
    k_fin<<<1, 1, 0, stream>>>(accF, accI, (float*)d_out);
}

// Round 2
// 106.868 us; speedup vs baseline: 2.3632x; 2.3632x over previous
//
#include <hip/hip_runtime.h>
#include <math.h>

#define EPS 1e-6f
#define DMAX 8
typedef unsigned long long ull;

__device__ __forceinline__ float waveSumF(float v) {
    #pragma unroll
    for (int m = 1; m < 64; m <<= 1) v += __shfl_xor(v, m, 64);
    return v;
}
__device__ __forceinline__ int waveSumI(int v) {
    #pragma unroll
    for (int m = 1; m < 64; m <<= 1) v += __shfl_xor(v, m, 64);
    return v;
}
__device__ __forceinline__ ull waveMinKey(ull v) {
    #pragma unroll
    for (int m = 1; m < 64; m <<= 1) {
        ull o = __shfl_xor(v, m, 64);
        v = (o < v) ? o : v;
    }
    return v;
}
__device__ __forceinline__ float sigmoidf(float x) {
    return 1.0f / (1.0f + expf(-x));
}

// accF/accI one 16-word buffer at d_ws start:
// F[0]=cal_sum F[1]=bf_sum F[2]=cx_sum  I[4]=cal_cnt I[5]=trip_cnt I[6]=ncalls I[7]=nputs

// K1: scalars + row norms + calendar (from raw inputs) + strike adjacency
__global__ void k_pre(const float* __restrict__ emb, const float* __restrict__ iv,
                      const float* __restrict__ geom, const float* __restrict__ liq,
                      const int* __restrict__ es, const int* __restrict__ em,
                      float* lwA, float* tvA, float* lmA, float* tenA, float* enA,
                      int* cpA, int* cnt, int* nbr, float* accF, int* accI,
                      int N, int ED, int Es, int Em) {
    const int tid  = blockIdx.x * blockDim.x + threadIdx.x;
    const int gsz  = gridDim.x * blockDim.x;
    const int lane = threadIdx.x & 63;

    // --- per-node scalars ---
    int ic = 0, ip = 0;
    for (int i = tid; i < N; i += gsz) {
        float lm = geom[3*i], ten = geom[3*i+1], cp = geom[3*i+2];
        lmA[i] = lm; tenA[i] = ten;
        int c = (cp > 0.5f) ? 1 : 0;
        ic += c; ip += (cp < 0.5f) ? 1 : 0;
        cpA[i] = c;
        lwA[i] = sigmoidf(liq[4*i+3]);
        float v = iv[i];
        tvA[i] = v * v * fmaxf(ten, EPS);
    }
    int sc = waveSumI(ic), sp = waveSumI(ip);
    if (lane == 0) {
        if (sc) atomicAdd(&accI[6], sc);
        if (sp) atomicAdd(&accI[7], sp);
    }

    // --- embedding row norms: one wave per row, float4 loads ---
    const int wid = tid >> 6, nw = gsz >> 6, ED4 = ED >> 2;
    for (int r = wid; r < N; r += nw) {
        const float4* row = (const float4*)(emb + (size_t)r * ED);
        float s = 0.f;
        for (int t = lane; t < ED4; t += 64) {
            float4 a = row[t];
            s += a.x*a.x + a.y*a.y + a.z*a.z + a.w*a.w;
        }
        s = waveSumF(s);
        if (lane == 0) enA[r] = sqrtf(s);
    }

    // --- calendar (recompute from raw inputs; no cross-block dependency) ---
    float c = 0.f; int n = 0;
    for (int e = tid; e < Em; e += gsz) {
        int s = em[e], d = em[Em + e];
        float ts = geom[3*s+1], td = geom[3*d+1];
        if (ts < td - EPS) {
            n++;
            float ivs = iv[s], ivd = iv[d];
            float tvs = ivs*ivs*fmaxf(ts, EPS), tvd = ivd*ivd*fmaxf(td, EPS);
            float lws = sigmoidf(liq[4*s+3]), lwd = sigmoidf(liq[4*d+3]);
            c += fminf(lws, lwd) * fmaxf(tvs - tvd, 0.f);
        }
    }
    c = waveSumF(c); n = waveSumI(n);
    if (lane == 0) {
        if (c != 0.f) atomicAdd(&accF[0], c);
        if (n) atomicAdd(&accI[4], n);
    }

    // --- strike adjacency (cnt pre-zeroed by memset) ---
    for (int e = tid; e < Es; e += gsz) {
        int s = es[e], d = es[Es + e];
        int p = atomicAdd(&cnt[s], 1); if (p < DMAX) nbr[s * DMAX + p] = d;
        p = atomicAdd(&cnt[d], 1);     if (p < DMAX) nbr[d * DMAX + p] = s;
    }
}

// K2: butterfly/convexity (first nBtf blocks) || put-argmin (remaining blocks)
__global__ void k_mid(const int* __restrict__ cnt, const int* __restrict__ nbr,
                      const int* __restrict__ cpA, const float* __restrict__ lmA,
                      const float* __restrict__ tenA, const float* __restrict__ lwA,
                      const float* __restrict__ tvA, const float* __restrict__ enA,
                      float* accF, int* accI, ull* partialKey,
                      int N, int nBtf, int nIB, int splitY, int chunk) {
    __shared__ float2 stile[256];

    if ((int)blockIdx.x < nBtf) {
        int i = blockIdx.x * blockDim.x + threadIdx.x;
        float bf = 0.f, cx = 0.f; int tc = 0;
        if (i < N) {
            int m = cnt[i]; if (m > DMAX) m = DMAX;
            int ids[DMAX]; float key[DMAX]; int mv = 0;
            for (int t = 0; t < m; t++) {
                int nb = nbr[i * DMAX + t];
                if (cpA[nb]) {
                    float k = lmA[nb];
                    int p = mv++;
                    while (p > 0 && key[p-1] > k) { key[p] = key[p-1]; ids[p] = ids[p-1]; p--; }
                    key[p] = k; ids[p] = nb;
                }
            }
            if (cpA[i] && mv >= 3) {
                float lwi = lwA[i];
                for (int j = 0; j + 2 < mv; j++) {
                    int n1 = ids[j], n2 = ids[j+1], n3 = ids[j+2];
                    float lm1 = key[j], lm2 = key[j+1], lm3 = key[j+2];
                    float denom = lm3 - lm1 + EPS;
                    float alpha = (lm3 - lm2) / denom;
                    float beta  = (lm2 - lm1) / denom;
                    float bviol = fmaxf(alpha * tvA[n1] + beta * tvA[n3] - tvA[n2], 0.f);
                    float xviol = fmaxf(enA[n2] - (alpha * enA[n1] + (1.0f - alpha) * enA[n3]), 0.f);
                    float w = lwi * lwA[n2];
                    bf += w * bviol; cx += w * xviol; tc++;
                }
            }
        }
        bf = waveSumF(bf); cx = waveSumF(cx); tc = waveSumI(tc);
        if ((threadIdx.x & 63) == 0) {
            if (bf != 0.f) atomicAdd(&accF[1], bf);
            if (cx != 0.f) atomicAdd(&accF[2], cx);
            if (tc) atomicAdd(&accI[5], tc);
        }
        return;
    }

    // argmin blocks: ab = y*nIB + ib
    int ab = blockIdx.x - nBtf;
    int ib = ab % nIB, y = ab / nIB;
    int i  = ib * 256 + threadIdx.x;
    float lmi  = (i < N) ? lmA[i]  : 0.f;
    float teni = (i < N) ? tenA[i] : 0.f;
    int j0 = y * chunk;
    int j1 = min(j0 + chunk, N);
    float mind0 = INFINITY, mind1 = INFINITY;
    int   minj0 = 0,        minj1 = 1;
    for (int t0 = j0; t0 < j1; t0 += 256) {
        __syncthreads();
        int jj = t0 + threadIdx.x;
        if (jj < N && cpA[jj] == 0)          // put: real coords
            stile[threadIdx.x] = make_float2(lmA[jj], tenA[jj]);
        else                                 // call or pad: poisoned lm -> dist ~1e38
            stile[threadIdx.x] = make_float2(1e19f, 0.f);
        __syncthreads();
        #pragma unroll 8
        for (int t = 0; t < 256; t += 2) {
            float2 p0 = stile[t], p1 = stile[t+1];
            float dl0 = lmi - p0.x, dt0 = teni - p0.y;
            float dl1 = lmi - p1.x, dt1 = teni - p1.y;
            float d0 = dl0*dl0 + dt0*dt0;
            float d1 = dl1*dl1 + dt1*dt1;
            if (d0 < mind0) { mind0 = d0; minj0 = t0 + t; }
            if (d1 < mind1) { mind1 = d1; minj1 = t0 + t + 1; }
        }
    }
    ull k0 = ((ull)__float_as_uint(mind0) << 32) | (unsigned)minj0;
    ull k1 = ((ull)__float_as_uint(mind1) << 32) | (unsigned)minj1;
    ull k  = (k1 < k0) ? k1 : k0;
    if (i < N) partialKey[(size_t)i * splitY + y] = k;
}

// K3: one wave per node i — reduce splitY keys, then pcp embedding distance
__global__ void k_post(const float* __restrict__ emb, const ull* __restrict__ partialKey,
                       const int* __restrict__ cpA, const float* __restrict__ lwA,
                       float* partialPcp, int N, int ED, int splitY) {
    __shared__ float sblk[4];
    const int lane = threadIdx.x & 63;
    const int w    = threadIdx.x >> 6;
    const int i    = (blockIdx.x * blockDim.x + threadIdx.x) >> 6;

    float contrib = 0.f;
    if (i < N) {
        ull k = (lane < splitY) ? partialKey[(size_t)i * splitY + lane] : ~0ULL;
        k = waveMinKey(k);
        int b = (int)(k & 0xffffffffULL);
        int iscall = cpA[i];
        float s = 0.f;
        if (iscall && b >= 0 && b < N) {
            const float4* ri = (const float4*)(emb + (size_t)i * ED);
            const float4* rb = (const float4*)(emb + (size_t)b * ED);
            const int ED4 = ED >> 2;
            for (int t = lane; t < ED4; t += 64) {
                float4 a = ri[t], c = rb[t];
                float dx = a.x-c.x, dy = a.y-c.y, dz = a.z-c.z, dw = a.w-c.w;
                s += dx*dx + dy*dy + dz*dz + dw*dw;
            }
            s = waveSumF(s);
            contrib = lwA[i] * lwA[b] * s;
        } else {
            s = waveSumF(0.f);   // keep wave converged (cheap)
        }
    }
    if (lane == 0) sblk[w] = contrib;
    __syncthreads();
    if (threadIdx.x == 0)
        partialPcp[blockIdx.x] = sblk[0] + sblk[1] + sblk[2] + sblk[3];
}

__global__ void k_fin(const float* __restrict__ accF, const int* __restrict__ accI,
                      const float* __restrict__ partialPcp, int nP, float* out) {
    __shared__ float sb[4];
    float s = 0.f;
    for (int t = threadIdx.x; t < nP; t += blockDim.x) s += partialPcp[t];
    s = waveSumF(s);
    if ((threadIdx.x & 63) == 0) sb[threadIdx.x >> 6] = s;
    __syncthreads();
    if (threadIdx.x == 0) {
        float pcpSum = sb[0] + sb[1] + sb[2] + sb[3];
        float cal = (accI[4] > 0) ? accF[0] / (float)max(accI[4], 1) : 0.f;
        int tcount = accI[5];
        float bf = (tcount > 0) ? accF[1] / (float)tcount : 0.f;
        float cx = (tcount > 0) ? accF[2] / (float)tcount : 0.f;
        float pcp = (accI[6] > 0 && accI[7] > 0) ? pcpSum / (float)max(accI[6], 1) : 0.f;
        out[0] = cal; out[1] = bf; out[2] = pcp; out[3] = cx;
        out[4] = cal + bf + 0.5f * pcp + 0.5f * cx;
    }
}

extern "C" void kernel_launch(void* const* d_in, const int* in_sizes, int n_in,
                              void* d_out, int out_size, void* d_ws, size_t ws_size,
                              hipStream_t stream) {
    const float* emb  = (const float*)d_in[0];   // (N,256)
    const float* iv   = (const float*)d_in[1];   // (N,1)
    const float* geom = (const float*)d_in[2];   // (N,3)
    const float* liq  = (const float*)d_in[3];   // (N,4)
    const int*   es   = (const int*)d_in[4];     // (2,Es)
    const int*   em   = (const int*)d_in[5];     // (2,Em)

    const int N  = in_sizes[1];
    const int ED = in_sizes[0] / N;
    const int Es = in_sizes[4] / 2;
    const int Em = in_sizes[5] / 2;

    // ws layout (words): [acc 16][cnt N][lw N][tv N][lm N][ten N][en N][cp N][nbr 8N][partialPcp nK3][pad][partialKey N*splitY ull]
    float* accF = (float*)d_ws;
    int*   accI = (int*)d_ws;
    int*   cnt  = (int*)d_ws + 16;
    float* lwA  = (float*)((int*)d_ws + 16 + N);
    float* tvA  = lwA + N;
    float* lmA  = tvA + N;
    float* tenA = lmA + N;
    float* enA  = tenA + N;
    int*   cpA  = (int*)(enA + N);
    int*   nbr  = cpA + N;

    const int B = 256;
    const int nK3 = (N + 3) / 4;                 // one wave per node, 4 waves/block
    float* partialPcp = (float*)(nbr + (size_t)DMAX * N);
    size_t keyOffB = ((size_t)((char*)(partialPcp + nK3) - (char*)d_ws) + 7) & ~(size_t)7;
    ull* partialKey = (ull*)((char*)d_ws + keyOffB);

    int splitY = 32;
    size_t availKey = (ws_size > keyOffB) ? (ws_size - keyOffB) : 0;
    int maxSplit = (int)(availKey / ((size_t)N * 8));
    if (splitY > maxSplit) splitY = maxSplit;
    if (splitY < 1) splitY = 1;
    if (splitY > 64) splitY = 64;
    int chunk = (N + splitY - 1) / splitY;
    chunk = ((chunk + 255) / 256) * 256;

    hipMemsetAsync(d_ws, 0, 64 + (size_t)N * 4, stream);   // acc + cnt

    k_pre<<<2048, B, 0, stream>>>(emb, iv, geom, liq, es, em,
                                  lwA, tvA, lmA, tenA, enA, cpA, cnt, nbr,
                                  accF, accI, N, ED, Es, Em);

    const int nIB  = (N + B - 1) / B;
    const int nBtf = (N + B - 1) / B;
    k_mid<<<nBtf + nIB * splitY, B, 0, stream>>>(cnt, nbr, cpA, lmA, tenA, lwA, tvA, enA,
                                                 accF, accI, partialKey,
                                                 N, nBtf, nIB, splitY, chunk);

    k_post<<<nK3, B, 0, stream>>>(emb, partialKey, cpA, lwA, partialPcp, N, ED, splitY);
    k_fin<<<1, B, 0, stream>>>(accF, accI, partialPcp, nK3, (float*)d_out);
}